// Round 1
// baseline (446.000 us; speedup 1.0000x reference)
//
#include <hip/hip_runtime.h>

#define B_ 512
#define T_ 512
#define C_ 128
#define L_ 80
#define S_ 161            // 2*L+1
#define BLANK_ 127
#define NEG_ (-1e30f)
#define EPS_ 1e-7f

// One block per batch element. Threads 0..S_-1 own one extended-label state
// each; threads 0..127 stage the y_pred row. Alpha for step t-1 lives in LDS
// with a 2-element NEG pad so a1/a2 shifts are branch-free.
__global__ __launch_bounds__(256) void ctc_kernel(
    const int* __restrict__ labels,      // [B, L] int32
    const float* __restrict__ y_pred,    // [B, T, C] float32
    float* __restrict__ out)             // [B, 1] float32
{
  const int b   = blockIdx.x;
  const int tid = threadIdx.x;

  __shared__ float row[2][C_];
  __shared__ float alpha_sh[S_ + 2];   // [0..1] = NEG pad, state s at s+2
  __shared__ float logdenom_sh;

  // Per-thread static state: extended symbol + skip-transition mask.
  int  ext    = BLANK_;
  bool allow2 = false;
  if (tid < S_) {
    if (tid & 1) {
      ext    = labels[b * L_ + (tid >> 1)];
      allow2 = (tid == 1) || (ext != labels[b * L_ + (tid >> 1) - 1]);
    }
  }
  if (tid < 2) alpha_sh[tid] = NEG_;

  const float* base = y_pred + (size_t)b * T_ * C_;
  if (tid < C_) row[0][tid] = base[tid];
  __syncthreads();

  float alpha = NEG_;
  int cur = 0;

  for (int t = 0; t < T_; ++t) {
    // ---- prefetch row t+1 into registers (hide HBM latency) ----
    float pre = 0.f;
    const bool has_next = (t + 1 < T_) && (tid < C_);
    if (has_next) pre = base[(size_t)(t + 1) * C_ + tid];

    // ---- read t-1 neighbors from LDS before anyone overwrites them ----
    float a1 = NEG_, a2 = NEG_;
    if (t > 0 && tid < S_) {
      a1 = alpha_sh[tid + 1];
      a2 = allow2 ? alpha_sh[tid] : NEG_;
    }

    // ---- row-sum (softmax denominator) on wave 0 ----
    if (tid < 64) {
      float v = row[cur][tid] + row[cur][tid + 64];
      #pragma unroll
      for (int off = 32; off > 0; off >>= 1)
        v += __shfl_xor(v, off, 64);
      if (tid == 0) logdenom_sh = __logf(v + C_ * EPS_);
    }
    __syncthreads();   // logdenom visible; all alpha_sh reads complete

    // ---- recurrence ----
    if (tid < S_) {
      const float lp = __logf(row[cur][ext] + EPS_) - logdenom_sh;
      if (t == 0) {
        alpha = (tid < 2) ? lp : NEG_;
      } else {
        const float m   = fmaxf(fmaxf(alpha, a1), a2);
        const float lse = m + __logf(__expf(alpha - m) + __expf(a1 - m) +
                                     __expf(a2 - m));
        alpha = lp + lse;
      }
      alpha_sh[tid + 2] = alpha;
    }
    if (has_next) row[cur ^ 1][tid] = pre;
    cur ^= 1;
    __syncthreads();   // writes visible for next iteration
  }

  // loss = -logaddexp(alpha[S-1], alpha[S-2])
  if (tid == 0) {
    const float x = alpha_sh[S_ + 1];
    const float y = alpha_sh[S_];
    const float m = fmaxf(x, y);
    out[b] = -(m + __logf(__expf(x - m) + __expf(y - m)));
  }
}

extern "C" void kernel_launch(void* const* d_in, const int* in_sizes, int n_in,
                              void* d_out, int out_size, void* d_ws, size_t ws_size,
                              hipStream_t stream) {
  const int*   labels = (const int*)d_in[0];    // y_true [B,L]
  const float* y_pred = (const float*)d_in[1];  // y_pred [B,T,C]
  float*       out    = (float*)d_out;          // [B,1]
  ctc_kernel<<<dim3(B_), dim3(256), 0, stream>>>(labels, y_pred, out);
}

// Round 2
// 345.557 us; speedup vs baseline: 1.2907x; 1.2907x over previous
//
#include <hip/hip_runtime.h>

#define B_ 512
#define T_ 512
#define C_ 128
#define L_ 80
#define S_ 161            // 2*L+1
#define BLANK_ 127
#define NEG_ (-1e30f)
#define EPS_ 1e-7f
#define DPF_ 8            // prefetch depth (time steps)

// ---------------------------------------------------------------------------
// Kernel A: per-batch sum of log row-sums.
//   lp[b,t,c] = log(p+eps) - log(rowsum + C*eps).  The -log(rowsum...) term is
//   uniform over states at each t, so it factors out of the whole CTC DP:
//   loss = S_b - logaddexp(raw159, raw160), S_b = sum_t log(rowsum_bt + C*eps).
//   Memory-bound: 134 MB coalesced float4. Grid (4 chunks, B) for occupancy.
// ---------------------------------------------------------------------------
__global__ __launch_bounds__(256) void ctc_denom(
    const float* __restrict__ y_pred,   // [B,T,C]
    float* __restrict__ Spart)          // [B,4]
{
  const int b = blockIdx.y, chunk = blockIdx.x;
  const int tid = threadIdx.x;
  const float4* base = (const float4*)(y_pred + (size_t)b * T_ * C_
                                       + (size_t)chunk * 128 * C_);
  float acc = 0.f;
  // 128 rows * 128 floats = 4096 float4; 256 threads -> 16 iters, 8 rows/iter.
  // Lanes 0..31 of each 32-group cover one row (32 float4 = 128 floats).
  #pragma unroll 4
  for (int i = 0; i < 16; ++i) {
    float4 v = base[i * 256 + tid];
    float s = (v.x + v.y) + (v.z + v.w);
    #pragma unroll
    for (int off = 16; off >= 1; off >>= 1)
      s += __shfl_xor(s, off, 64);
    if ((tid & 31) == 0) acc += __logf(s + C_ * EPS_);
  }
  __shared__ float part[8];
  if ((tid & 31) == 0) part[tid >> 5] = acc;
  __syncthreads();
  if (tid == 0) {
    float t = 0.f;
    #pragma unroll
    for (int k = 0; k < 8; ++k) t += part[k];
    Spart[b * 4 + chunk] = t;
  }
}

// ---------------------------------------------------------------------------
// Kernel B: the alpha chain. One wave per batch, blocked 3 states/lane
// (lane i owns states 3i..3i+2), zero barriers. Neighbors via 2 shfl_up.
// Gathers p[ext] prefetched DPF_ steps deep (y_pred is LLC-resident after A).
// ---------------------------------------------------------------------------
__global__ __launch_bounds__(64) void ctc_chain(
    const int* __restrict__ labels,     // [B,L]
    const float* __restrict__ y_pred,   // [B,T,C]
    const float* __restrict__ Spart,    // [B,4]
    float* __restrict__ out)            // [B,1]
{
  const int b = blockIdx.x;
  const int lane = threadIdx.x;
  const float* base = y_pred + (size_t)b * T_ * C_;

  // Static per-lane state: extended symbol + skip mask for 3 states.
  int e0 = BLANK_, e1 = BLANK_, e2 = BLANK_;
  bool al0 = false, al1 = false, al2 = false;
  {
    const int s0 = 3 * lane, s1 = s0 + 1, s2 = s0 + 2;
    if (s0 <= 160 && (s0 & 1)) {
      int k = s0 >> 1; e0 = labels[b * L_ + k];
      al0 = (k == 0) || (e0 != labels[b * L_ + k - 1]);
    }
    if (s1 <= 160 && (s1 & 1)) {
      int k = s1 >> 1; e1 = labels[b * L_ + k];
      al1 = (k == 0) || (e1 != labels[b * L_ + k - 1]);
    }
    if (s2 <= 160 && (s2 & 1)) {
      int k = s2 >> 1; e2 = labels[b * L_ + k];
      al2 = (k == 0) || (e2 != labels[b * L_ + k - 1]);
    }
  }

  // Prefetch pipeline: slot j holds the 3 gathered p values for time tb+j.
  float g0[DPF_], g1[DPF_], g2[DPF_];
  #pragma unroll
  for (int j = 0; j < DPF_; ++j) {
    g0[j] = base[j * C_ + e0];
    g1[j] = base[j * C_ + e1];
    g2[j] = base[j * C_ + e2];
  }

  float A0 = NEG_, A1 = NEG_, A2 = NEG_;

  for (int tb = 0; tb < T_; tb += DPF_) {
    #pragma unroll
    for (int j = 0; j < DPF_; ++j) {
      const int t = tb + j;
      // lp (off critical path — pure ILP while shuffles are in flight)
      const float lp0 = __logf(g0[j] + EPS_);
      const float lp1 = __logf(g1[j] + EPS_);
      const float lp2 = __logf(g2[j] + EPS_);
      // neighbors from lane-1 (prev step's alpha)
      float p1 = __shfl_up(A1, 1);
      float p2 = __shfl_up(A2, 1);
      if (lane == 0) { p1 = NEG_; p2 = NEG_; }
      // s=3i:   a1 = prev[3i-1]=p2, a2 = prev[3i-2]=p1
      // s=3i+1: a1 = prev[3i]=A0,  a2 = prev[3i-1]=p2
      // s=3i+2: a1 = prev[3i+1]=A1, a2 = prev[3i]=A0
      const float b2_0 = al0 ? p1 : NEG_;
      const float b2_1 = al1 ? p2 : NEG_;
      const float b2_2 = al2 ? A0 : NEG_;

      const float m0 = fmaxf(fmaxf(A0, p2), b2_0);
      const float m1 = fmaxf(fmaxf(A1, A0), b2_1);
      const float m2 = fmaxf(fmaxf(A2, A1), b2_2);
      float n0 = lp0 + m0 + __logf(__expf(A0 - m0) + __expf(p2 - m0) + __expf(b2_0 - m0));
      float n1 = lp1 + m1 + __logf(__expf(A1 - m1) + __expf(A0 - m1) + __expf(b2_1 - m1));
      float n2 = lp2 + m2 + __logf(__expf(A2 - m2) + __expf(A1 - m2) + __expf(b2_2 - m2));
      if (t == 0) {            // uniform branch, taken once
        const bool l0 = (lane == 0);
        n0 = l0 ? lp0 : NEG_;
        n1 = l0 ? lp1 : NEG_;
        n2 = NEG_;
      }
      A0 = n0; A1 = n1; A2 = n2;
      // prefetch time t+DPF_ into this slot (clamped; tail loads redundant)
      int tn = t + DPF_; if (tn > T_ - 1) tn = T_ - 1;
      g0[j] = base[tn * C_ + e0];
      g1[j] = base[tn * C_ + e1];
      g2[j] = base[tn * C_ + e2];
    }
  }

  // loss = S_b - logaddexp(raw[160], raw[159]);  states 159,160 = lane53 A0,A1
  if (lane == 53) {
    const float x = A1, y = A0;
    const float m = fmaxf(x, y);
    const float lse = m + __logf(__expf(x - m) + __expf(y - m));
    const float S = (Spart[b * 4 + 0] + Spart[b * 4 + 1]) +
                    (Spart[b * 4 + 2] + Spart[b * 4 + 3]);
    out[b] = S - lse;
  }
}

extern "C" void kernel_launch(void* const* d_in, const int* in_sizes, int n_in,
                              void* d_out, int out_size, void* d_ws, size_t ws_size,
                              hipStream_t stream) {
  const int*   labels = (const int*)d_in[0];    // y_true [B,L]
  const float* y_pred = (const float*)d_in[1];  // y_pred [B,T,C]
  float*       out    = (float*)d_out;          // [B,1]
  float*       Spart  = (float*)d_ws;           // [B,4] partial denom sums

  ctc_denom<<<dim3(4, B_), dim3(256), 0, stream>>>(y_pred, Spart);
  ctc_chain<<<dim3(B_), dim3(64), 0, stream>>>(labels, y_pred, Spart, out);
}

// Round 4
// 241.927 us; speedup vs baseline: 1.8435x; 1.4284x over previous
//
#include <hip/hip_runtime.h>

#define B_ 512
#define T_ 512
#define C_ 128
#define L_ 80
#define S_ 161            // 2*L+1
#define BLANK_ 127
#define NEG_ (-1e30f)
#define EPS_ 1e-7f
#define CEPS_ (128.0f * 1e-7f)
#define LN2_ 0.6931471805599453f

// raw v_exp_f32 / v_log_f32 (base-2). NOTE: __exp2f/__log2f collide with
// glibc math.h reserved names — use the amdgcn builtins directly.
#define EXP2F(x) __builtin_amdgcn_exp2f(x)
#define LOG2F(x) __builtin_amdgcn_logf(x)

// Single fused kernel. One wave per batch element.
//  - lane i owns extended states 3i..3i+2; neighbor alphas via 2x shfl_up.
//  - y_pred rows staged coalesced into a wave-private 4-slot LDS ring
//    (wave-synchronous: in-order DS pipe, no barriers); the 3 p[ext] gathers
//    per lane are ds_read_b32 issued a full 4-step block ahead.
//  - softmax denominator factors out of the DP (uniform over states at each
//    t): loss = ln2 * (sum_t log2(rowsum_t + C*eps) - log2addexp(a159,a160)).
//    Row sums computed from the staging registers: 16-lane groups own one of
//    the 4 staged rows (7 in-lane adds + 4 shfl_xor levels + 1 log2 per row).
__global__ __launch_bounds__(64) void ctc_fused(
    const int* __restrict__ labels,     // [B,L]
    const float* __restrict__ y_pred,   // [B,T,C]
    float* __restrict__ out)            // [B,1]
{
  const int b    = blockIdx.x;
  const int lane = threadIdx.x;
  const float4* rp = (const float4*)(y_pred + (size_t)b * T_ * C_);

  __shared__ float ring[4 * C_];        // 4 row slots

  // ---- static per-lane state: extended symbols + skip masks ----
  int e0 = BLANK_, e1 = BLANK_, e2 = BLANK_;
  bool al0 = false, al1 = false, al2 = false;
  {
    const int s0 = 3 * lane, s1 = s0 + 1, s2 = s0 + 2;
    if (s0 <= 160 && (s0 & 1)) {
      int k = s0 >> 1; e0 = labels[b * L_ + k];
      al0 = (k == 0) || (e0 != labels[b * L_ + k - 1]);
    }
    if (s1 <= 160 && (s1 & 1)) {
      int k = s1 >> 1; e1 = labels[b * L_ + k];
      al1 = (k == 0) || (e1 != labels[b * L_ + k - 1]);
    }
    if (s2 <= 160 && (s2 & 1)) {
      int k = s2 >> 1; e2 = labels[b * L_ + k];
      al2 = (k == 0) || (e2 != labels[b * L_ + k - 1]);
    }
  }

  // ---- row staging: lane = 16g+i; group g owns row tb+g, floats 8i..8i+7 ----
  const int g = lane >> 4, i = lane & 15;
  const int fidx = 2 * i;               // float4 index within row (row = 32 f4)

  // prologue: rows 0..3 -> regs -> ring; rows 4..7 in flight
  float4 c0 = rp[g * 32 + fidx], c1 = rp[g * 32 + fidx + 1];
  {
    float4* ws = (float4*)(ring + g * C_ + 8 * i);
    ws[0] = c0; ws[1] = c1;
  }
  float4 n0 = rp[(4 + g) * 32 + fidx], n1 = rp[(4 + g) * 32 + fidx + 1];

  // prologue gathers for rows 0..3
  float ga0[4], ga1[4], ga2[4];
  #pragma unroll
  for (int j = 0; j < 4; ++j) {
    ga0[j] = ring[j * C_ + e0];
    ga1[j] = ring[j * C_ + e1];
    ga2[j] = ring[j * C_ + e2];
  }

  float A0 = NEG_, A1 = NEG_, A2 = NEG_;
  float Sacc = 0.f;

  for (int tb = 0; tb < T_; tb += 4) {
    // ---- 4 alpha steps (gathers were issued a block ago) ----
    #pragma unroll
    for (int j = 0; j < 4; ++j) {
      const int t = tb + j;
      const float lp0 = LOG2F(ga0[j] + EPS_);
      const float lp1 = LOG2F(ga1[j] + EPS_);
      const float lp2 = LOG2F(ga2[j] + EPS_);
      float p1 = __shfl_up(A1, 1);
      float p2 = __shfl_up(A2, 1);
      if (lane == 0) { p1 = NEG_; p2 = NEG_; }
      // s=3i:   a1=prev[3i-1]=p2, a2=prev[3i-2]=p1
      // s=3i+1: a1=prev[3i]=A0,   a2=prev[3i-1]=p2
      // s=3i+2: a1=prev[3i+1]=A1, a2=prev[3i]=A0
      const float b2_0 = al0 ? p1 : NEG_;
      const float b2_1 = al1 ? p2 : NEG_;
      const float b2_2 = al2 ? A0 : NEG_;
      const float m0 = fmaxf(fmaxf(A0, p2), b2_0);
      const float m1 = fmaxf(fmaxf(A1, A0), b2_1);
      const float m2 = fmaxf(fmaxf(A2, A1), b2_2);
      float n0a = lp0 + m0 + LOG2F(EXP2F(A0 - m0) + EXP2F(p2 - m0) + EXP2F(b2_0 - m0));
      float n1a = lp1 + m1 + LOG2F(EXP2F(A1 - m1) + EXP2F(A0 - m1) + EXP2F(b2_1 - m1));
      float n2a = lp2 + m2 + LOG2F(EXP2F(A2 - m2) + EXP2F(A1 - m2) + EXP2F(b2_2 - m2));
      if (t == 0) {                     // uniform scalar branch, cheap
        const bool l0 = (lane == 0);
        n0a = l0 ? lp0 : NEG_;
        n1a = l0 ? lp1 : NEG_;
        n2a = NEG_;
      }
      A0 = n0a; A1 = n1a; A2 = n2a;
    }

    // ---- stage rows tb+4..tb+7 into ring (after all gathers of tb..tb+3;
    //      in-order DS pipe keeps ordering correct, no barrier needed) ----
    {
      float4* ws = (float4*)(ring + g * C_ + 8 * i);
      ws[0] = n0; ws[1] = n1;
    }
    // ---- issue gathers for rows tb+4..tb+7 (consumed next block) ----
    #pragma unroll
    for (int j = 0; j < 4; ++j) {
      ga0[j] = ring[j * C_ + e0];
      ga1[j] = ring[j * C_ + e1];
      ga2[j] = ring[j * C_ + e2];
    }
    // ---- denominator: rowsum of rows tb..tb+3 from staging regs ----
    {
      float s = ((c0.x + c0.y) + (c0.z + c0.w)) + ((c1.x + c1.y) + (c1.z + c1.w));
      s += __shfl_xor(s, 8, 16);
      s += __shfl_xor(s, 4, 16);
      s += __shfl_xor(s, 2, 16);
      s += __shfl_xor(s, 1, 16);
      Sacc += LOG2F(s + CEPS_);         // group g accumulates its rows
    }
    // ---- rotate + prefetch rows tb+8..tb+11 (clamped) ----
    c0 = n0; c1 = n1;
    int rn = tb + 8 + g; if (rn > T_ - 1) rn = T_ - 1;
    n0 = rp[rn * 32 + fidx];
    n1 = rp[rn * 32 + fidx + 1];
  }

  // ---- total denom across the 4 lane-groups ----
  Sacc += __shfl_xor(Sacc, 16, 64);
  Sacc += __shfl_xor(Sacc, 32, 64);

  // loss = ln2 * (S - log2addexp(raw160, raw159)); lane 53: A0=s159, A1=s160
  if (lane == 53) {
    const float x = A1, y = A0;
    const float m = fmaxf(x, y);
    const float lse2 = m + LOG2F(EXP2F(x - m) + EXP2F(y - m));
    out[b] = LN2_ * (Sacc - lse2);
  }
}

extern "C" void kernel_launch(void* const* d_in, const int* in_sizes, int n_in,
                              void* d_out, int out_size, void* d_ws, size_t ws_size,
                              hipStream_t stream) {
  const int*   labels = (const int*)d_in[0];    // y_true [B,L]
  const float* y_pred = (const float*)d_in[1];  // y_pred [B,T,C]
  float*       out    = (float*)d_out;          // [B,1]
  ctc_fused<<<dim3(B_), dim3(64), 0, stream>>>(labels, y_pred, out);
}

// Round 5
// 192.604 us; speedup vs baseline: 2.3156x; 1.2561x over previous
//
#include <hip/hip_runtime.h>

#define B_ 512
#define T_ 512
#define C_ 128
#define L_ 80
#define BLANK_ 127
#define EPS_ 1e-7f
#define LN2_ 0.6931471805599453f

// raw v_log_f32 (base-2); __log2f collides with glibc math.h reserved names.
#define LOG2F(x) __builtin_amdgcn_logf(x)

// DPP cross-lane ops (VALU pipe — keeps the DS pipe off the critical path).
template <int CTRL>
__device__ __forceinline__ int dpp_i(int x) {
  return __builtin_amdgcn_update_dpp(0, x, CTRL, 0xF, 0xF, true);
}
template <int CTRL>
__device__ __forceinline__ float dpp_f(float x) {
  return __int_as_float(
      __builtin_amdgcn_update_dpp(0, __float_as_int(x), CTRL, 0xF, 0xF, true));
}
#define DPP_WSHR1 0x138   // wave shift right 1 == shfl_up(1); lane0 -> 0
#define DPP_XOR1  0xB1    // quad_perm [1,0,3,2]
#define DPP_XOR2  0x4E    // quad_perm [2,3,0,1]
#define DPP_HMIRR 0x141   // row_half_mirror (within 8)
#define DPP_MIRR  0x140   // row_mirror (within 16)

// One wave per batch element. Lane i owns extended states 3i..3i+2.
// Linear-probability DP: alpha_new = p*(a0 + a1 + m*a2) — no transcendentals
// in the chain. Per-lane scale exponent E (stored = true * 2^E), rescaled
// every 8-step block; neighbor values reconciled with ldexp by d = E - E_left.
// Neighbor exchange via DPP wave_shr1 (VALU). y_pred staged in 8-row blocks:
// global float4 loads (2-block lead) -> LDS ring (2 banks) -> per-lane
// ds_read_b32 gathers of the 1-2 label symbols + broadcast blank.
// Softmax denominator factors out: loss = ln2*(Σ log2(rowsum_t) - log2 lse).
__global__ __launch_bounds__(64) void ctc_fused(
    const int* __restrict__ labels,     // [B,L]
    const float* __restrict__ y_pred,   // [B,T,C]
    float* __restrict__ out)            // [B,1]
{
  const int b = blockIdx.x, lane = threadIdx.x;
  const float4* rp = (const float4*)(y_pred + (size_t)b * T_ * C_);
  __shared__ float ring[2 * 8 * C_];    // 2 banks x 8 rows x 128 floats

  const int rgrp = lane >> 3, j16 = lane & 7;   // row-group, slot within row
  const bool evenLane = ((lane & 1) == 0);

  // ---- static per-lane symbols + skip masks ----
  // even lane i: states blank / label k1=3i/2 / blank
  // odd  lane i: states label k0=(3i-1)/2 / blank / label k2=k0+1
  auto labAt = [&](int k) -> int {
    return (k >= 0 && k < L_) ? labels[b * L_ + k] : BLANK_;
  };
  int ea, eb;
  float m0, m1, m2;                     // allow-skip masks as 0.0/1.0
  if (evenLane) {
    const int k1 = (3 * lane) >> 1;
    ea = labAt(k1); eb = ea;
    m0 = 0.f; m2 = 0.f;
    m1 = ((k1 < L_) && (k1 == 0 || ea != labAt(k1 - 1))) ? 1.f : 0.f;
  } else {
    const int k0 = (3 * lane - 1) >> 1;
    const int k2 = k0 + 1;
    ea = labAt(k0); eb = labAt(k2);
    m0 = ((k0 < L_) && (k0 == 0 || ea != labAt(k0 - 1))) ? 1.f : 0.f;
    m1 = 0.f;
    m2 = ((k2 < L_) && (eb != ea)) ? 1.f : 0.f;
  }

  // ---- prologue: issue loads for blocks 0,1,2 ----
  float4 S0[4], S1[4], S2[4];
  {
    const float4* p0 = rp + (0 * 8 + rgrp) * 32 + 4 * j16;
    const float4* p1 = rp + (1 * 8 + rgrp) * 32 + 4 * j16;
    const float4* p2 = rp + (2 * 8 + rgrp) * 32 + 4 * j16;
    #pragma unroll
    for (int k = 0; k < 4; ++k) { S0[k] = p0[k]; S1[k] = p1[k]; S2[k] = p2[k]; }
  }

  float Sacc = 0.f;                     // per-lane partial: Σ log2(rowsum)

  // eps-add, stage to ring bank, fused row-sum (8-lane DPP reduce) + log2
  auto prep = [&](float4 (&Sw)[4], int bankDst) {
    #pragma unroll
    for (int k = 0; k < 4; ++k) {
      Sw[k].x += EPS_; Sw[k].y += EPS_; Sw[k].z += EPS_; Sw[k].w += EPS_;
    }
    float4* wd = (float4*)(ring + bankDst * 1024 + rgrp * C_ + 16 * j16);
    #pragma unroll
    for (int k = 0; k < 4; ++k) wd[k] = Sw[k];
    float s = 0.f;
    #pragma unroll
    for (int k = 0; k < 4; ++k)
      s += (Sw[k].x + Sw[k].y) + (Sw[k].z + Sw[k].w);
    s += dpp_f<DPP_XOR1>(s);
    s += dpp_f<DPP_XOR2>(s);
    s += dpp_f<DPP_HMIRR>(s);           // all 8 lanes of the row share the sum
    Sacc += LOG2F(s);                   // 8x redundant; divided out at the end
  };

  prep(S0, 0);                          // block 0 -> bank 0

  // virtual init: one recurrence step from (A0=1@lane0) yields exact alpha(t=0)
  float A0 = (lane == 0) ? 1.f : 0.f, A1 = 0.f, A2 = 0.f;
  int E = 0;
  float ga[8], gb[8], pb[8];

  auto body = [&](int n, float4 (&Sld)[4], float4 (&Swr)[4], bool doPrep) {
    const int bank = n & 1;
    const int EL = dpp_i<DPP_WSHR1>(E); // left lane's exponent (lane0 -> 0)
    const int d = E - EL;               // block-constant reconcile shift
    // gathers for this block (issued up front; latency amortized over 8 steps)
    const float* rb = ring + bank * 1024;
    #pragma unroll
    for (int j = 0; j < 8; ++j) {
      ga[j] = rb[j * C_ + ea];
      gb[j] = rb[j * C_ + eb];
      pb[j] = rb[j * C_ + BLANK_];      // same addr all lanes: LDS broadcast
    }
    // global loads block n+3 (2-block lead over consumption)
    {
      int r8 = (n + 3) * 8 + rgrp; if (r8 > T_ - 1) r8 = T_ - 1;
      const float4* src = rp + r8 * 32 + 4 * j16;
      #pragma unroll
      for (int k = 0; k < 4; ++k) Sld[k] = src[k];
    }
    if (doPrep) prep(Swr, bank ^ 1);    // stage block n+1, fuse its denominator
    // ---- 8 DP steps ----
    #pragma unroll
    for (int j = 0; j < 8; ++j) {
      const float p1 = dpp_f<DPP_WSHR1>(A1);   // left A1 (state 3i-2)
      const float p2 = dpp_f<DPP_WSHR1>(A2);   // left A2 (state 3i-1)
      const float p1p = ldexpf(p1, d);
      const float p2p = ldexpf(p2, d);
      const float q0 = evenLane ? pb[j] : ga[j];
      const float q1 = evenLane ? ga[j] : pb[j];
      const float q2 = evenLane ? pb[j] : gb[j];
      const float t0 = q0 * fmaf(m0, p1p, A0 + p2p);
      const float t1 = q1 * fmaf(m1, p2p, A1 + A0);
      const float t2 = q2 * fmaf(m2, A0, A2 + A1);
      A0 = t0; A1 = t1; A2 = t2;
    }
    // ---- per-lane rescale: keep lane max ~2^0, fold into E ----
    {
      const float mx = fmaxf(fmaxf(A0, A1), A2);
      int ee = (int)((__float_as_uint(mx) >> 23) & 255u) - 127;
      const bool z = (mx == 0.f);
      ee = z ? 0 : ee;
      A0 = ldexpf(A0, -ee); A1 = ldexpf(A1, -ee); A2 = ldexpf(A2, -ee);
      E = z ? EL : (E - ee);            // virgin lanes track left neighbor's E
    }
  };

  for (int nn = 0; nn < 63; nn += 3) {  // blocks 0..62 (S-set rotation mod 3)
    body(nn,     S0, S1, true);
    body(nn + 1, S1, S2, true);
    body(nn + 2, S2, S0, true);
  }
  body(63, S0, S1, false);              // last block: no staging/prefetch

  // ---- denominator total (each row counted 8x -> *0.125) ----
  float s = Sacc;
  s += dpp_f<DPP_XOR1>(s);
  s += dpp_f<DPP_XOR2>(s);
  s += dpp_f<DPP_HMIRR>(s);
  s += dpp_f<DPP_MIRR>(s);
  s += __shfl_xor(s, 16, 64);
  s += __shfl_xor(s, 32, 64);
  const float Stot = s * 0.125f;

  // loss = ln2 * (S - (log2(A159+A160) - E));  lane 53: A0=s159, A1=s160
  if (lane == 53) {
    const float lse2 = LOG2F(A0 + A1) - (float)E;
    out[b] = LN2_ * (Stot - lse2);
  }
}

extern "C" void kernel_launch(void* const* d_in, const int* in_sizes, int n_in,
                              void* d_out, int out_size, void* d_ws, size_t ws_size,
                              hipStream_t stream) {
  const int*   labels = (const int*)d_in[0];    // y_true [B,L]
  const float* y_pred = (const float*)d_in[1];  // y_pred [B,T,C]
  float*       out    = (float*)d_out;          // [B,1]
  ctc_fused<<<dim3(B_), dim3(64), 0, stream>>>(labels, y_pred, out);
}